// Round 4
// baseline (281.590 us; speedup 1.0000x reference)
//
#include <hip/hip_runtime.h>
#include <math.h>

// GSchNet continuous-filter convolution edge embedding.
// out[e,:] = f(dist(e)) where f: R -> R^128 (RBF+MLP) is a smooth function of
// ONE scalar. Tabulate f on [0,16] at 4096 steps, lerp per edge.
// R2: 115us (known good: A 4097-blk build ~14, B dist ~6, C 4-slot lerp ~90).
// R3: 244us REGRESSION (changed A-fusion AND C-unroll together; unattributed).
// R4: revert to R2 structure; ONE change: standalone multi-row A (4 rows share
//     each W load -> 8x less L2 traffic). B and C byte-identical to R2.

#define N_NODES_C   50000
#define N_EDGES_C   800000
#define LATENT_C    128
#define N_CENTERS_C 100
#define TABK        4096
#define DMAX        16.0f
#define LN2F        0.69314718056f
#define NA_BLOCKS   513          // 513 blocks * 8 rows = 4104 >= 4097 table rows

typedef float v4f __attribute__((ext_vector_type(4)));

__device__ __forceinline__ float shifted_softplus(float x) {
    return fmaxf(x, 0.0f) + log1pf(expf(-fabsf(x))) - LN2F;
}

// -------- Phase A: multi-row table build. 256 thr = 2 sub-blocks x 128; each
// sub-block computes 4 consecutive rows, amortizing W1/W2 loads 4x.
__global__ void build_table_kernel(const float* __restrict__ W1, const float* __restrict__ b1,
                                   const float* __restrict__ W2, const float* __restrict__ b2,
                                   float* __restrict__ table) {
    __shared__ float rbf[2][4][N_CENTERS_C];   // 400B rows -> 16B aligned
    __shared__ float hbuf[2][4][LATENT_C];
    const int sub  = threadIdx.x >> 7;         // 0..1
    const int j    = threadIdx.x & 127;
    const int row0 = blockIdx.x * 8 + sub * 4;

    if (j < N_CENTERS_C) {
        const float c = (float)j * (10.0f / 99.0f);   // linspace(0,10,100)
        #pragma unroll
        for (int r = 0; r < 4; ++r) {
            const float d = (float)(row0 + r) * (DMAX / (float)TABK);
            const float x = d - c;
            rbf[sub][r][j] = expf(-x * x);
        }
    }
    __syncthreads();

    // layer 1: a_r[j] = b1[j] + sum_c rbf[r][c] * W1[c][j]
    float a0 = b1[j], a1 = a0, a2 = a0, a3 = a0;
    for (int c = 0; c < N_CENTERS_C; c += 4) {
        const float w0 = W1[(c + 0) * LATENT_C + j];
        const float w1 = W1[(c + 1) * LATENT_C + j];
        const float w2 = W1[(c + 2) * LATENT_C + j];
        const float w3 = W1[(c + 3) * LATENT_C + j];
        const v4f r0 = *(const v4f*)&rbf[sub][0][c];   // broadcast ds_read_b128
        const v4f r1 = *(const v4f*)&rbf[sub][1][c];
        const v4f r2 = *(const v4f*)&rbf[sub][2][c];
        const v4f r3 = *(const v4f*)&rbf[sub][3][c];
        a0 = fmaf(r0[0], w0, fmaf(r0[1], w1, fmaf(r0[2], w2, fmaf(r0[3], w3, a0))));
        a1 = fmaf(r1[0], w0, fmaf(r1[1], w1, fmaf(r1[2], w2, fmaf(r1[3], w3, a1))));
        a2 = fmaf(r2[0], w0, fmaf(r2[1], w1, fmaf(r2[2], w2, fmaf(r2[3], w3, a2))));
        a3 = fmaf(r3[0], w0, fmaf(r3[1], w1, fmaf(r3[2], w2, fmaf(r3[3], w3, a3))));
    }
    hbuf[sub][0][j] = shifted_softplus(a0);
    hbuf[sub][1][j] = shifted_softplus(a1);
    hbuf[sub][2][j] = shifted_softplus(a2);
    hbuf[sub][3][j] = shifted_softplus(a3);
    __syncthreads();

    // layer 2: o_r[j] = b2[j] + sum_i h[r][i] * W2[i][j]
    float o0 = b2[j], o1 = o0, o2 = o0, o3 = o0;
    for (int i = 0; i < LATENT_C; i += 4) {
        const float w0 = W2[(i + 0) * LATENT_C + j];
        const float w1 = W2[(i + 1) * LATENT_C + j];
        const float w2 = W2[(i + 2) * LATENT_C + j];
        const float w3 = W2[(i + 3) * LATENT_C + j];
        const v4f h0 = *(const v4f*)&hbuf[sub][0][i];
        const v4f h1 = *(const v4f*)&hbuf[sub][1][i];
        const v4f h2 = *(const v4f*)&hbuf[sub][2][i];
        const v4f h3 = *(const v4f*)&hbuf[sub][3][i];
        o0 = fmaf(h0[0], w0, fmaf(h0[1], w1, fmaf(h0[2], w2, fmaf(h0[3], w3, o0))));
        o1 = fmaf(h1[0], w0, fmaf(h1[1], w1, fmaf(h1[2], w2, fmaf(h1[3], w3, o1))));
        o2 = fmaf(h2[0], w0, fmaf(h2[1], w1, fmaf(h2[2], w2, fmaf(h2[3], w3, o2))));
        o3 = fmaf(h3[0], w0, fmaf(h3[1], w1, fmaf(h3[2], w2, fmaf(h3[3], w3, o3))));
    }
    #pragma unroll
    for (int r = 0; r < 4; ++r) {
        const int row = row0 + r;
        const float o = (r == 0) ? o0 : (r == 1) ? o1 : (r == 2) ? o2 : o3;
        if (row <= TABK) table[(size_t)row * LATENT_C + j] = o;
    }
}

// -------- Phase B: thread-per-edge table coordinate (identical to R2)
__global__ void compute_t_kernel(const float* __restrict__ nodes,
                                 const int* __restrict__ senders,
                                 const int* __restrict__ receivers,
                                 float* __restrict__ tcoord) {
    const int e = blockIdx.x * blockDim.x + threadIdx.x;
    if (e >= N_EDGES_C) return;
    const int s = senders[e];
    const int r = receivers[e];
    const float dx = nodes[3 * s + 0] - nodes[3 * r + 0];
    const float dy = nodes[3 * s + 1] - nodes[3 * r + 1];
    const float dz = nodes[3 * s + 2] - nodes[3 * r + 2];
    const float dist = sqrtf(fmaf(dx, dx, fmaf(dy, dy, dz * dz)));
    // clamp so k+1 <= TABK stays in table
    tcoord[e] = fminf(dist * ((float)TABK / DMAX), (float)TABK - 0.5f);
}

// -------- Phase C: half-wave (32 lanes x float4) per edge; 2 slots = 4 edges/iter.
// Non-temporal stores keep table + tcoord L2-resident. (identical to R2)
__global__ void edge_write_kernel(const float* __restrict__ tcoord,
                                  const float* __restrict__ table,
                                  float* __restrict__ out) {
    const int lane = threadIdx.x & 63;
    const int half = lane >> 5;          // edge within a slot
    const int li   = lane & 31;          // float4 index within the 128-f row
    const int wid  = (blockIdx.x * blockDim.x + threadIdx.x) >> 6;
    const int nw   = (gridDim.x * blockDim.x) >> 6;

    for (int base = wid * 4; base + 3 < N_EDGES_C; base += nw * 4) {
        // slot 0: edges base, base+1 ; slot 1: edges base+2, base+3
        const float t0 = tcoord[base + half];
        const float t1 = tcoord[base + 2 + half];
        const int   k0 = (int)t0;  const float f0 = t0 - (float)k0;
        const int   k1 = (int)t1;  const float f1 = t1 - (float)k1;

        const v4f* r0 = (const v4f*)(table + (size_t)k0 * LATENT_C);
        const v4f* r1 = (const v4f*)(table + (size_t)k1 * LATENT_C);
        const v4f a0 = r0[li], b0 = r0[li + 32];   // +32 v4f = next row (k0+1)
        const v4f a1 = r1[li], b1 = r1[li + 32];

        v4f o0, o1;
        #pragma unroll
        for (int c = 0; c < 4; ++c) {
            o0[c] = fmaf(f0, b0[c] - a0[c], a0[c]);
            o1[c] = fmaf(f1, b1[c] - a1[c], a1[c]);
        }

        v4f* po0 = (v4f*)(out + (size_t)base * LATENT_C);        // covers edges base,base+1
        v4f* po1 = (v4f*)(out + (size_t)(base + 2) * LATENT_C);  // covers edges base+2,base+3
        __builtin_nontemporal_store(o0, &po0[lane]);
        __builtin_nontemporal_store(o1, &po1[lane]);
    }
}

// -------- Fallback (ws too small): direct per-edge MLP
__global__ void edge_direct_kernel(const float* __restrict__ nodes,
                                   const int* __restrict__ senders,
                                   const int* __restrict__ receivers,
                                   const float* __restrict__ W1, const float* __restrict__ b1,
                                   const float* __restrict__ W2, const float* __restrict__ b2,
                                   float* __restrict__ out) {
    __shared__ float rbf[N_CENTERS_C];
    __shared__ float hbuf[LATENT_C];
    const int j = threadIdx.x;

    for (int e = blockIdx.x; e < N_EDGES_C; e += gridDim.x) {
        const int s = senders[e];
        const int r = receivers[e];
        const float dx = nodes[3 * s + 0] - nodes[3 * r + 0];
        const float dy = nodes[3 * s + 1] - nodes[3 * r + 1];
        const float dz = nodes[3 * s + 2] - nodes[3 * r + 2];
        const float dist = sqrtf(fmaf(dx, dx, fmaf(dy, dy, dz * dz)));

        if (j < N_CENTERS_C) {
            const float c = (float)j * (10.0f / 99.0f);
            const float x = dist - c;
            rbf[j] = expf(-x * x);
        }
        __syncthreads();

        float a = b1[j];
        #pragma unroll 4
        for (int c = 0; c < N_CENTERS_C; ++c)
            a = fmaf(rbf[c], W1[c * LATENT_C + j], a);
        hbuf[j] = shifted_softplus(a);
        __syncthreads();

        float o = b2[j];
        #pragma unroll 4
        for (int i = 0; i < LATENT_C; ++i)
            o = fmaf(hbuf[i], W2[i * LATENT_C + j], o);
        out[(size_t)e * LATENT_C + j] = o;

        __syncthreads();
    }
}

extern "C" void kernel_launch(void* const* d_in, const int* in_sizes, int n_in,
                              void* d_out, int out_size, void* d_ws, size_t ws_size,
                              hipStream_t stream) {
    const float* nodes     = (const float*)d_in[0];
    const int*   senders   = (const int*)  d_in[1];
    const int*   receivers = (const int*)  d_in[2];
    const float* W1        = (const float*)d_in[3];
    const float* b1        = (const float*)d_in[4];
    const float* W2        = (const float*)d_in[5];
    const float* b2        = (const float*)d_in[6];
    float*       out       = (float*)d_out;

    const size_t table_bytes = (size_t)(TABK + 1) * LATENT_C * sizeof(float); // 2,097,664
    const size_t t_bytes     = (size_t)N_EDGES_C * sizeof(float);             // 3,200,000

    if (ws_size >= table_bytes + t_bytes) {
        float* table  = (float*)d_ws;
        float* tcoord = (float*)((char*)d_ws + table_bytes);

        build_table_kernel<<<NA_BLOCKS, 256, 0, stream>>>(W1, b1, W2, b2, table);
        compute_t_kernel<<<(N_EDGES_C + 255) / 256, 256, 0, stream>>>(nodes, senders,
                                                                      receivers, tcoord);
        // 2048 blocks x 4 waves = 8192 waves = exactly the 256CU x 32wave residency cap
        edge_write_kernel<<<2048, 256, 0, stream>>>(tcoord, table, out);
    } else {
        edge_direct_kernel<<<16384, LATENT_C, 0, stream>>>(nodes, senders, receivers,
                                                           W1, b1, W2, b2, out);
    }
}

// Round 5
// 114.128 us; speedup vs baseline: 2.4673x; 2.4673x over previous
//
#include <hip/hip_runtime.h>
#include <math.h>

// GSchNet continuous-filter convolution edge embedding.
// out[e,:] = f(dist(e)) where f: R -> R^128 (RBF+MLP) is a smooth function of
// ONE scalar. Tabulate f on [0,16] at 4096 steps, lerp per edge.
//
// ROUND 5 = REPRODUCIBILITY PROBE: byte-identical resubmission of the R2
// source that measured 115us. R3 (244us) and R4 (281us) both regressed with
// changes that cannot analytically cost >10us; this probe decides between
// "multi-row A has an unknown 160us mechanism" and "bench noise ~ +-100us".
//   A) build table (4097x128 f32, 2.1 MB in ws)
//   B) compute per-edge table coordinate t[e] (3.2 MB in ws)
//   C) half-wave-per-edge float4 lerp + NON-TEMPORAL stores (keep L2 for table)

#define N_NODES_C   50000
#define N_EDGES_C   800000
#define LATENT_C    128
#define N_CENTERS_C 100
#define TABK        4096
#define DMAX        16.0f
#define LN2F        0.69314718056f

typedef float v4f __attribute__((ext_vector_type(4)));

__device__ __forceinline__ float shifted_softplus(float x) {
    return fmaxf(x, 0.0f) + log1pf(expf(-fabsf(x))) - LN2F;
}

// -------- Phase A: one block (128 threads) per table row k, d = k*(DMAX/TABK)
__global__ void build_table_kernel(const float* __restrict__ W1, const float* __restrict__ b1,
                                   const float* __restrict__ W2, const float* __restrict__ b2,
                                   float* __restrict__ table) {
    __shared__ float rbf[N_CENTERS_C];
    __shared__ float hbuf[LATENT_C];
    const int j = threadIdx.x;
    const float d = (float)blockIdx.x * (DMAX / (float)TABK);

    if (j < N_CENTERS_C) {
        const float c = (float)j * (10.0f / 99.0f);   // linspace(0,10,100)
        const float x = d - c;
        rbf[j] = expf(-x * x);
    }
    __syncthreads();

    float a = b1[j];
    #pragma unroll 4
    for (int c = 0; c < N_CENTERS_C; ++c)
        a = fmaf(rbf[c], W1[c * LATENT_C + j], a);
    hbuf[j] = shifted_softplus(a);
    __syncthreads();

    float o = b2[j];
    #pragma unroll 4
    for (int i = 0; i < LATENT_C; ++i)
        o = fmaf(hbuf[i], W2[i * LATENT_C + j], o);

    table[(size_t)blockIdx.x * LATENT_C + j] = o;
}

// -------- Phase B: thread-per-edge table coordinate
__global__ void compute_t_kernel(const float* __restrict__ nodes,
                                 const int* __restrict__ senders,
                                 const int* __restrict__ receivers,
                                 float* __restrict__ tcoord) {
    const int e = blockIdx.x * blockDim.x + threadIdx.x;
    if (e >= N_EDGES_C) return;
    const int s = senders[e];
    const int r = receivers[e];
    const float dx = nodes[3 * s + 0] - nodes[3 * r + 0];
    const float dy = nodes[3 * s + 1] - nodes[3 * r + 1];
    const float dz = nodes[3 * s + 2] - nodes[3 * r + 2];
    const float dist = sqrtf(fmaf(dx, dx, fmaf(dy, dy, dz * dz)));
    // clamp so k+1 <= TABK stays in table
    tcoord[e] = fminf(dist * ((float)TABK / DMAX), (float)TABK - 0.5f);
}

// -------- Phase C: half-wave (32 lanes x float4) per edge; 2 slots = 4 edges/iter.
// Non-temporal stores keep table + tcoord L2-resident.
__global__ void edge_write_kernel(const float* __restrict__ tcoord,
                                  const float* __restrict__ table,
                                  float* __restrict__ out) {
    const int lane = threadIdx.x & 63;
    const int half = lane >> 5;          // edge within a slot
    const int li   = lane & 31;          // float4 index within the 128-f row
    const int wid  = (blockIdx.x * blockDim.x + threadIdx.x) >> 6;
    const int nw   = (gridDim.x * blockDim.x) >> 6;

    for (int base = wid * 4; base + 3 < N_EDGES_C; base += nw * 4) {
        // slot 0: edges base, base+1 ; slot 1: edges base+2, base+3
        const float t0 = tcoord[base + half];
        const float t1 = tcoord[base + 2 + half];
        const int   k0 = (int)t0;  const float f0 = t0 - (float)k0;
        const int   k1 = (int)t1;  const float f1 = t1 - (float)k1;

        const v4f* r0 = (const v4f*)(table + (size_t)k0 * LATENT_C);
        const v4f* r1 = (const v4f*)(table + (size_t)k1 * LATENT_C);
        const v4f a0 = r0[li], b0 = r0[li + 32];   // +32 v4f = next row (k0+1)
        const v4f a1 = r1[li], b1 = r1[li + 32];

        v4f o0, o1;
        #pragma unroll
        for (int c = 0; c < 4; ++c) {
            o0[c] = fmaf(f0, b0[c] - a0[c], a0[c]);
            o1[c] = fmaf(f1, b1[c] - a1[c], a1[c]);
        }

        v4f* po0 = (v4f*)(out + (size_t)base * LATENT_C);        // covers edges base,base+1
        v4f* po1 = (v4f*)(out + (size_t)(base + 2) * LATENT_C);  // covers edges base+2,base+3
        __builtin_nontemporal_store(o0, &po0[lane]);
        __builtin_nontemporal_store(o1, &po1[lane]);
    }
}

// -------- Fallback (ws too small): direct per-edge MLP
__global__ void edge_direct_kernel(const float* __restrict__ nodes,
                                   const int* __restrict__ senders,
                                   const int* __restrict__ receivers,
                                   const float* __restrict__ W1, const float* __restrict__ b1,
                                   const float* __restrict__ W2, const float* __restrict__ b2,
                                   float* __restrict__ out) {
    __shared__ float rbf[N_CENTERS_C];
    __shared__ float hbuf[LATENT_C];
    const int j = threadIdx.x;

    for (int e = blockIdx.x; e < N_EDGES_C; e += gridDim.x) {
        const int s = senders[e];
        const int r = receivers[e];
        const float dx = nodes[3 * s + 0] - nodes[3 * r + 0];
        const float dy = nodes[3 * s + 1] - nodes[3 * r + 1];
        const float dz = nodes[3 * s + 2] - nodes[3 * r + 2];
        const float dist = sqrtf(fmaf(dx, dx, fmaf(dy, dy, dz * dz)));

        if (j < N_CENTERS_C) {
            const float c = (float)j * (10.0f / 99.0f);
            const float x = dist - c;
            rbf[j] = expf(-x * x);
        }
        __syncthreads();

        float a = b1[j];
        #pragma unroll 4
        for (int c = 0; c < N_CENTERS_C; ++c)
            a = fmaf(rbf[c], W1[c * LATENT_C + j], a);
        hbuf[j] = shifted_softplus(a);
        __syncthreads();

        float o = b2[j];
        #pragma unroll 4
        for (int i = 0; i < LATENT_C; ++i)
            o = fmaf(hbuf[i], W2[i * LATENT_C + j], o);
        out[(size_t)e * LATENT_C + j] = o;

        __syncthreads();
    }
}

extern "C" void kernel_launch(void* const* d_in, const int* in_sizes, int n_in,
                              void* d_out, int out_size, void* d_ws, size_t ws_size,
                              hipStream_t stream) {
    const float* nodes     = (const float*)d_in[0];
    const int*   senders   = (const int*)  d_in[1];
    const int*   receivers = (const int*)  d_in[2];
    const float* W1        = (const float*)d_in[3];
    const float* b1        = (const float*)d_in[4];
    const float* W2        = (const float*)d_in[5];
    const float* b2        = (const float*)d_in[6];
    float*       out       = (float*)d_out;

    const size_t table_bytes = (size_t)(TABK + 1) * LATENT_C * sizeof(float); // 2,097,664
    const size_t t_bytes     = (size_t)N_EDGES_C * sizeof(float);             // 3,200,000

    if (ws_size >= table_bytes + t_bytes) {
        float* table  = (float*)d_ws;
        float* tcoord = (float*)((char*)d_ws + table_bytes);

        build_table_kernel<<<TABK + 1, LATENT_C, 0, stream>>>(W1, b1, W2, b2, table);
        compute_t_kernel<<<(N_EDGES_C + 255) / 256, 256, 0, stream>>>(nodes, senders,
                                                                      receivers, tcoord);
        // 2048 blocks x 4 waves = 8192 waves = exactly the 256CU x 32wave residency cap
        edge_write_kernel<<<2048, 256, 0, stream>>>(tcoord, table, out);
    } else {
        edge_direct_kernel<<<16384, LATENT_C, 0, stream>>>(nodes, senders, receivers,
                                                           W1, b1, W2, b2, out);
    }
}